// Round 1
// baseline (522.191 us; speedup 1.0000x reference)
//
#include <hip/hip_runtime.h>

// ---------- types / helpers ----------
typedef __bf16 bf16x8 __attribute__((ext_vector_type(8)));
typedef float  f32x4  __attribute__((ext_vector_type(4)));
typedef unsigned short u16;

__device__ __forceinline__ u16 f2bf(float f) {
  unsigned u = __builtin_bit_cast(unsigned, f);
  u += 0x7fffu + ((u >> 16) & 1u);           // round-to-nearest-even
  return (u16)(u >> 16);
}

using gvoid = __attribute__((address_space(1))) void;
using svoid = __attribute__((address_space(3))) void;
__device__ __forceinline__ void load_lds16(const void* g, void* s) {
  __builtin_amdgcn_global_load_lds((const gvoid*)g, (svoid*)s, 16, 0, 0);
}

// ---------- transpose + fp32->bf16 convert: F[b][c][n] -> FT[b][n][c] ----------
// grid (N/32, C/32, B), block (32,8)
__global__ void transpose_cvt(const float* __restrict__ F, u16* __restrict__ FT) {
  __shared__ float tile[32][33];
  const int b = blockIdx.z;
  const int n0 = blockIdx.x * 32, c0 = blockIdx.y * 32;
  const float* Fb = F + (long)b * 2048 * 1024;
  u16* FTb = FT + (long)b * 1024 * 2048;
  const int tx = threadIdx.x, ty = threadIdx.y;
#pragma unroll
  for (int i = 0; i < 4; ++i)
    tile[ty + i * 8][tx] = Fb[(long)(c0 + ty + i * 8) * 1024 + n0 + tx];
  __syncthreads();
#pragma unroll
  for (int i = 0; i < 4; ++i)
    FTb[(long)(n0 + ty + i * 8) * 2048 + c0 + tx] = f2bf(tile[tx][ty + i * 8]);
}

// ---------- fp32 -> bf16 convert (vectorized), n4 = quads ----------
__global__ void cvt_bf16(const float* __restrict__ in, u16* __restrict__ out, int n4) {
  int i = blockIdx.x * 256 + threadIdx.x;
  if (i < n4) {
    float4 v = ((const float4*)in)[i];
    ushort4 o;
    o.x = f2bf(v.x); o.y = f2bf(v.y); o.z = f2bf(v.z); o.w = f2bf(v.w);
    ((ushort4*)out)[i] = o;
  }
}

// ---------- generic bf16 GEMM: D[m][n] = sum_k A[m][k]*B[n][k] (+bias) ----------
// 128x128 tile, BK=64, 256 threads (2x2 waves of 64x64).
// LDS tiles [row][k] with st-style XOR swizzle; staged via global_load_lds
// (linear dest + inverse-swizzled SOURCE, swizzle on READ — rule #21).
// BIAS_MODE: 0 none, 1 bias[col], 2 bias[row]. OUT_BF16: 1 bf16 store else f32.
template <int OUT_BF16, int BIAS_MODE>
__global__ __launch_bounds__(256) void gemm_bt(
    const u16* __restrict__ A, const u16* __restrict__ B, void* __restrict__ Dv,
    const float* __restrict__ bias, int K, int lda, int ldb, int ldd,
    long sA_, long sB_, long sD_) {
  __shared__ char sm[32768];
  char* sA = sm;
  char* sB = sm + 16384;
  const int z = blockIdx.z;
  const u16* Ab = A + (long)z * sA_;
  const u16* Bb = B + (long)z * sB_;
  const int m0 = blockIdx.y * 128, n0 = blockIdx.x * 128;
  const int t = threadIdx.x;
  const int w = t >> 6, l = t & 63;
  const int wm = w >> 1, wn = w & 1;
  const int lhi = l >> 4, llo = l & 15;
  // staging: lane l covers physical (row = chunk*8 + (l>>3), colbyte = (l&7)*16)
  const int srow = l >> 3;
  const int scolb = (((l & 7) ^ srow) << 4);     // inverse-swizzled source column
  const int swz = (l & 7) << 4;                  // read-side XOR (row&7)<<4
  f32x4 acc[4][4] = {};
  int abase[4], bbase[4];
#pragma unroll
  for (int f = 0; f < 4; ++f) {
    abase[f] = (wm * 64 + f * 16 + llo) * 128;
    bbase[f] = (wn * 64 + f * 16 + llo) * 128;
  }
  const int in0 = (0 * 64 + lhi * 16) ^ swz;     // ks=0 inner byte offset
  const int in1 = (1 * 64 + lhi * 16) ^ swz;     // ks=1

  for (int k0 = 0; k0 < K; k0 += 64) {
#pragma unroll
    for (int i = 0; i < 4; ++i) {
      const int ci = i * 4 + w;                  // 16 chunks of 8 rows
      const int row = ci * 8 + srow;
      load_lds16((const char*)(Ab + (long)(m0 + row) * lda + k0) + scolb,
                 sA + ci * 1024);
      load_lds16((const char*)(Bb + (long)(n0 + row) * ldb + k0) + scolb,
                 sB + ci * 1024);
    }
    asm volatile("s_waitcnt vmcnt(0)" ::: "memory");
    __syncthreads();
#pragma unroll
    for (int ks = 0; ks < 2; ++ks) {
      const int inner = ks ? in1 : in0;
      bf16x8 af[4], bfr[4];
#pragma unroll
      for (int f = 0; f < 4; ++f) {
        af[f]  = *(const bf16x8*)(sA + abase[f] + inner);
        bfr[f] = *(const bf16x8*)(sB + bbase[f] + inner);
      }
#pragma unroll
      for (int fm = 0; fm < 4; ++fm)
#pragma unroll
        for (int fn = 0; fn < 4; ++fn)
          acc[fm][fn] = __builtin_amdgcn_mfma_f32_16x16x32_bf16(
              af[fm], bfr[fn], acc[fm][fn], 0, 0, 0);
    }
    __syncthreads();
  }

  // epilogue: C/D layout col = lane&15, row = (lane>>4)*4 + j (verified m89)
  float* Df = (float*)Dv;
  u16* Dh = (u16*)Dv;
#pragma unroll
  for (int fm = 0; fm < 4; ++fm) {
    const int row = m0 + wm * 64 + fm * 16 + lhi * 4;
#pragma unroll
    for (int fn = 0; fn < 4; ++fn) {
      const int col = n0 + wn * 64 + fn * 16 + llo;
      const float cb = (BIAS_MODE == 1) ? bias[col] : 0.0f;
      f32x4 v = acc[fm][fn];
#pragma unroll
      for (int j = 0; j < 4; ++j) {
        float x = v[j] + cb;
        if (BIAS_MODE == 2) x += bias[row + j];
        const long idx = (long)z * sD_ + (long)(row + j) * ldd + col;
        if (OUT_BF16) Dh[idx] = f2bf(x);
        else          Df[idx] = x;
      }
    }
  }
}

// ---------- row softmax: S[8192][1024] f32 -> P bf16, softmax(alpha*s) ----------
__global__ void softmax_rows(const float* __restrict__ S, u16* __restrict__ P,
                             float alpha) {
  const long row = blockIdx.x;
  const int t = threadIdx.x, l = t & 63, w = t >> 6;
  float4 v = ((const float4*)(S + row * 1024))[t];
  __shared__ float red[8];
  float m = fmaxf(fmaxf(v.x, v.y), fmaxf(v.z, v.w));
#pragma unroll
  for (int off = 32; off; off >>= 1) m = fmaxf(m, __shfl_xor(m, off));
  if (l == 0) red[w] = m;
  __syncthreads();
  m = fmaxf(fmaxf(red[0], red[1]), fmaxf(red[2], red[3]));
  float e0 = __expf((v.x - m) * alpha);
  float e1 = __expf((v.y - m) * alpha);
  float e2 = __expf((v.z - m) * alpha);
  float e3 = __expf((v.w - m) * alpha);
  float s = e0 + e1 + e2 + e3;
#pragma unroll
  for (int off = 32; off; off >>= 1) s += __shfl_xor(s, off);
  if (l == 0) red[4 + w] = s;
  __syncthreads();
  s = red[4] + red[5] + red[6] + red[7];
  const float inv = 1.0f / s;
  ushort4 o;
  o.x = f2bf(e0 * inv); o.y = f2bf(e1 * inv);
  o.z = f2bf(e2 * inv); o.w = f2bf(e3 * inv);
  ((ushort4*)(P + row * 1024))[t] = o;
}

// ---------- F_final = AW[b][0] + AW[b][1] ----------
__global__ void final_add(const float4* __restrict__ aw, float4* __restrict__ dst) {
  const long i = (long)blockIdx.x * 256 + threadIdx.x;  // 2,097,152 quads
  const long b = i >> 19;                                // 524288 quads per [c][n]
  const long r = i & 524287;
  float4 a = aw[b * 1048576 + r];
  float4 c = aw[b * 1048576 + 524288 + r];
  float4 o;
  o.x = a.x + c.x; o.y = a.y + c.y; o.z = a.z + c.z; o.w = a.w + c.w;
  dst[i] = o;
}

// ---------- launch ----------
extern "C" void kernel_launch(void* const* d_in, const int* in_sizes, int n_in,
                              void* d_out, int out_size, void* d_ws, size_t ws_size,
                              hipStream_t stream) {
  (void)in_sizes; (void)n_in; (void)out_size; (void)ws_size;
  const float* F_rgb = (const float*)d_in[0];
  const float* F_ind = (const float*)d_in[1];
  // W/b order: q_rgb, k_rgb, v_rgb, q_ind, k_ind, v_ind
  const float* Wsrc[6] = {(const float*)d_in[2],  (const float*)d_in[4],
                          (const float*)d_in[6],  (const float*)d_in[8],
                          (const float*)d_in[10], (const float*)d_in[12]};
  const float* bias[6] = {(const float*)d_in[3],  (const float*)d_in[5],
                          (const float*)d_in[7],  (const float*)d_in[9],
                          (const float*)d_in[11], (const float*)d_in[13]};

  char* ws = (char*)d_ws;
  u16* FT_rgb = (u16*)(ws);                         // [4][1024][2048] bf16
  u16* FT_ind = (u16*)(ws + 16777216);
  u16* Wc[6];
  for (int i = 0; i < 6; ++i) Wc[i] = (u16*)(ws + 33554432 + (size_t)i * 8388608);
  u16* QT_rgb = (u16*)(ws + 83886080);              // [4][1024][2048]
  u16* KT_rgb = (u16*)(ws + 100663296);
  u16* QT_ind = (u16*)(ws + 117440512);
  u16* KT_ind = (u16*)(ws + 134217728);
  u16* V_rgb  = (u16*)(ws + 150994944);             // [4][2048][1024]
  u16* V_ind  = (u16*)(ws + 167772160);
  float* S    = (float*)(ws + 184549376);           // [2][4][1024][1024] f32
  u16*   P    = (u16*)(ws + 218103808);             // [2][4][1024][1024] bf16

  float* out       = (float*)d_out;
  float* out_final = out;                   // [4][2048][1024]
  float* out_Frgb  = out + 8388608;
  float* out_Find  = out + 16777216;
  float* AW        = out + 25165824;        // [4][2][2048][1024]

  // 1) transpose+convert inputs; convert weights
  transpose_cvt<<<dim3(32, 64, 4), dim3(32, 8), 0, stream>>>(F_rgb, FT_rgb);
  transpose_cvt<<<dim3(32, 64, 4), dim3(32, 8), 0, stream>>>(F_ind, FT_ind);
  for (int i = 0; i < 6; ++i)
    cvt_bf16<<<4096, 256, 0, stream>>>(Wsrc[i], Wc[i], 1048576);

  // 2) Q/K convs: QT[n][o] = sum_c FT[n][c] W[o][c] + b[o]   (col bias)
  gemm_bt<1, 1><<<dim3(16, 8, 4), 256, 0, stream>>>(FT_rgb, Wc[0], QT_rgb, bias[0],
      2048, 2048, 2048, 2048, 2097152L, 0L, 2097152L);
  gemm_bt<1, 1><<<dim3(16, 8, 4), 256, 0, stream>>>(FT_rgb, Wc[1], KT_rgb, bias[1],
      2048, 2048, 2048, 2048, 2097152L, 0L, 2097152L);
  gemm_bt<1, 1><<<dim3(16, 8, 4), 256, 0, stream>>>(FT_ind, Wc[3], QT_ind, bias[3],
      2048, 2048, 2048, 2048, 2097152L, 0L, 2097152L);
  gemm_bt<1, 1><<<dim3(16, 8, 4), 256, 0, stream>>>(FT_ind, Wc[4], KT_ind, bias[4],
      2048, 2048, 2048, 2048, 2097152L, 0L, 2097152L);
  // 3) V convs: V[c][n] = sum_c' Wv[c][c'] FT[n][c'] + b[c]  (row bias)
  gemm_bt<1, 2><<<dim3(8, 16, 4), 256, 0, stream>>>(Wc[2], FT_rgb, V_rgb, bias[2],
      2048, 2048, 2048, 1024, 0L, 2097152L, 2097152L);
  gemm_bt<1, 2><<<dim3(8, 16, 4), 256, 0, stream>>>(Wc[5], FT_ind, V_ind, bias[5],
      2048, 2048, 2048, 1024, 0L, 2097152L, 2097152L);

  // 4) scores: dir0 = Q_rgb x K_ind, dir1 = Q_ind x K_rgb  (f32 out)
  gemm_bt<0, 0><<<dim3(8, 8, 4), 256, 0, stream>>>(QT_rgb, KT_ind, S, nullptr,
      2048, 2048, 2048, 1024, 2097152L, 2097152L, 1048576L);
  gemm_bt<0, 0><<<dim3(8, 8, 4), 256, 0, stream>>>(QT_ind, KT_rgb, S + 4194304,
      nullptr, 2048, 2048, 2048, 1024, 2097152L, 2097152L, 1048576L);

  // 5) softmax rows (scale 1/sqrt(2048) folded in)
  softmax_rows<<<8192, 256, 0, stream>>>(S, P, 0.02209708691207961f);

  // 6) PV: attended[c][n] = sum_m V[c][m] P[n][m] -> straight into AW slots
  gemm_bt<0, 0><<<dim3(8, 16, 4), 256, 0, stream>>>(V_ind, P, AW, nullptr,
      1024, 1024, 1024, 1024, 2097152L, 1048576L, 4194304L);
  gemm_bt<0, 0><<<dim3(8, 16, 4), 256, 0, stream>>>(V_rgb, P + 4194304,
      AW + 2097152, nullptr,
      1024, 1024, 1024, 1024, 2097152L, 1048576L, 4194304L);

  // 7) F_final + identity passthroughs
  final_add<<<8192, 256, 0, stream>>>((const float4*)AW, (float4*)out_final);
  hipMemcpyAsync(out_Frgb, F_rgb, 33554432, hipMemcpyDeviceToDevice, stream);
  hipMemcpyAsync(out_Find, F_ind, 33554432, hipMemcpyDeviceToDevice, stream);
}

// Round 2
// 394.509 us; speedup vs baseline: 1.3236x; 1.3236x over previous
//
#include <hip/hip_runtime.h>

typedef __bf16 bf16x8 __attribute__((ext_vector_type(8)));
typedef float  f32x4  __attribute__((ext_vector_type(4)));
typedef unsigned short u16;

__device__ __forceinline__ u16 f2bf(float f) {
  unsigned u = __builtin_bit_cast(unsigned, f);
  u += 0x7fffu + ((u >> 16) & 1u);           // round-to-nearest-even
  return (u16)(u >> 16);
}

using gvoid = __attribute__((address_space(1))) void;
using svoid = __attribute__((address_space(3))) void;
__device__ __forceinline__ void load_lds16(const void* g, void* s) {
  __builtin_amdgcn_global_load_lds((const gvoid*)g, (svoid*)s, 16, 0, 0);
}

// ---------- transpose + fp32->bf16 convert: F[b][c][n] -> FT[b][n][c] ----------
__global__ void transpose_cvt(const float* __restrict__ F, u16* __restrict__ FT) {
  __shared__ float tile[32][33];
  const int b = blockIdx.z;
  const int n0 = blockIdx.x * 32, c0 = blockIdx.y * 32;
  const float* Fb = F + (long)b * 2048 * 1024;
  u16* FTb = FT + (long)b * 1024 * 2048;
  const int tx = threadIdx.x, ty = threadIdx.y;
#pragma unroll
  for (int i = 0; i < 4; ++i)
    tile[ty + i * 8][tx] = Fb[(long)(c0 + ty + i * 8) * 1024 + n0 + tx];
  __syncthreads();
#pragma unroll
  for (int i = 0; i < 4; ++i)
    FTb[(long)(n0 + ty + i * 8) * 2048 + c0 + tx] = f2bf(tile[tx][ty + i * 8]);
}

// ---------- fp32 -> bf16 convert (vectorized), n4 = quads ----------
__global__ void cvt_bf16(const float* __restrict__ in, u16* __restrict__ out, int n4) {
  int i = blockIdx.x * 256 + threadIdx.x;
  if (i < n4) {
    float4 v = ((const float4*)in)[i];
    ushort4 o;
    o.x = f2bf(v.x); o.y = f2bf(v.y); o.z = f2bf(v.z); o.w = f2bf(v.w);
    ((ushort4*)out)[i] = o;
  }
}

// ================= 256x256 8-phase bf16 GEMM: D[m][n] = A[m][k]*B[n][k] =================
// 512 threads = 8 waves (2x4 over each 128x128 C-quadrant; per-wave slice 64x32/quadrant).
// LDS 128 KiB: 2 buffers x {A0,A1,B0,B1} half-tiles of [128][64] bf16, XOR-swizzled
// (linear global_load_lds dest + inverse-swizzled global source + swizzled ds_read).
// Schedule: 8 phases / 2 K-tiles; stage stream runs ahead; vmcnt(4) gates at ph4/ph8
// BEFORE the barrier (all waves confirm own loads -> all chunks landed). Loads never
// drain to 0 across barriers (T4). setprio(1) around MFMA clusters (T5).
// Two parameter sets selected by blockIdx.z >= zsplit (for fused dual launches).

#define BAR_ do { asm volatile("" ::: "memory"); __builtin_amdgcn_s_barrier(); \
                  asm volatile("" ::: "memory"); } while (0)
#define VMW asm volatile("s_waitcnt vmcnt(4)" ::: "memory")

#define STG(Mp, ld, row0, kt, off)                                                 \
  do {                                                                             \
    load_lds16(Mp + (long)((row0) + w * 8 + srow) * (ld) + (kt) * 64 + scol,       \
               sm + (off) + w * 1024);                                             \
    load_lds16(Mp + (long)((row0) + 64 + w * 8 + srow) * (ld) + (kt) * 64 + scol,  \
               sm + (off) + 8192 + w * 1024);                                      \
  } while (0)

#define RDA(off)                                                                   \
  _Pragma("unroll") for (int fm = 0; fm < 4; ++fm)                                 \
  _Pragma("unroll") for (int ks = 0; ks < 2; ++ks)                                 \
    fa[fm][ks] = *(const bf16x8*)(sm + (off) + aoff[fm] + kin[ks]);

#define RDB(off, dst)                                                              \
  _Pragma("unroll") for (int fn = 0; fn < 2; ++fn)                                 \
  _Pragma("unroll") for (int ks = 0; ks < 2; ++ks)                                 \
    dst[fn][ks] = *(const bf16x8*)(sm + (off) + boff[fn] + kin[ks]);

#define MMQ(qa, qb, fb)                                                            \
  __builtin_amdgcn_s_setprio(1);                                                   \
  _Pragma("unroll") for (int fm = 0; fm < 4; ++fm)                                 \
  _Pragma("unroll") for (int fn = 0; fn < 2; ++fn)                                 \
  _Pragma("unroll") for (int ks = 0; ks < 2; ++ks)                                 \
    acc[qa][qb][fm][fn] = __builtin_amdgcn_mfma_f32_16x16x32_bf16(                 \
        fa[fm][ks], fb[fn][ks], acc[qa][qb][fm][fn], 0, 0, 0);                     \
  __builtin_amdgcn_s_setprio(0);

template <int OUT_BF16, int BIAS_MODE>   // BIAS: 0 none, 1 col (split@2048), 2 row
__global__ __launch_bounds__(512, 2) void gemm256(
    const u16* __restrict__ A0p, const u16* __restrict__ B0p, void* __restrict__ D0p,
    const float* __restrict__ ba0, const float* __restrict__ bb0,
    const u16* __restrict__ A1p, const u16* __restrict__ B1p, void* __restrict__ D1p,
    const float* __restrict__ ba1, const float* __restrict__ bb1,
    int zsplit, int K, int lda, int ldb, int ldd,
    long sA, long sB, long sD) {
  __shared__ __attribute__((aligned(128))) char sm[131072];
  const int zb = blockIdx.z;
  const bool s1 = (zb >= zsplit);
  const int zz = s1 ? zb - zsplit : zb;
  const u16* Ag = (s1 ? A1p : A0p) + (long)zz * sA;
  const u16* Bg = (s1 ? B1p : B0p) + (long)zz * sB;
  char* Dg = (char*)(s1 ? D1p : D0p) + (long)zz * sD * (OUT_BF16 ? 2 : 4);
  const float* ba = s1 ? ba1 : ba0;
  const float* bb = s1 ? bb1 : bb0;
  const int m0 = blockIdx.y * 256, n0 = blockIdx.x * 256;
  const int t = threadIdx.x, w = t >> 6, l = t & 63;
  const int wr = w >> 2, wc = w & 3;             // 2x4 waves within a quadrant
  const int lm = l & 15, lk = l >> 4;
  const int swz = (l & 7) << 4;                  // read-side XOR: (row&7)<<4, row&7==l&7
  const int srow = l >> 3;
  const int scol = ((l & 7) ^ srow) << 3;        // inverse-swizzled source col (elems)
  int aoff[4], boff[2], kin[2];
#pragma unroll
  for (int fm = 0; fm < 4; ++fm) aoff[fm] = (wr * 64 + fm * 16 + lm) * 128;
#pragma unroll
  for (int fn = 0; fn < 2; ++fn) boff[fn] = (wc * 32 + fn * 16 + lm) * 128;
  kin[0] = (lk * 16) ^ swz;
  kin[1] = (64 + lk * 16) ^ swz;

  f32x4 acc[2][2][4][2] = {};
  bf16x8 fa[4][2], fb0[2][2], fb1[2][2];

  const int nt = K >> 6;                         // K-tiles of 64 (nt even: K=1024/2048)

  // prologue: tiles 0 (4 halves) + tile 1 (A0,B0); gate first 4, leave 2 in flight
  STG(Ag, lda, m0,       0, 0);                  // buf0.A0
  STG(Bg, ldb, n0,       0, 32768);              // buf0.B0
  STG(Ag, lda, m0 + 128, 0, 16384);              // buf0.A1
  STG(Bg, ldb, n0 + 128, 0, 49152);              // buf0.B1
  STG(Ag, lda, m0,       1, 65536);              // buf1.A0
  STG(Bg, ldb, n0,       1, 65536 + 32768);      // buf1.B0
  VMW;
  BAR_;

  for (int u = 0; u < nt; u += 2) {
    const int t2 = (u + 2 < nt) ? u + 2 : nt - 1;   // clamped prefetch (redundant ok)
    const int t3 = (u + 3 < nt) ? u + 3 : nt - 1;
    // ph1: tile u, Q(0,0); reads buf0.A0/B0 (done ph1-2 -> A0 restage ph3 safe)
    RDA(0); RDB(32768, fb0);
    STG(Ag, lda, m0 + 128, u + 1, 65536 + 16384);   // buf1.A1 <- A1[u+1]
    BAR_; MMQ(0, 0, fb0); BAR_;
    // ph2: Q(0,1); reuse fa
    RDB(49152, fb1);
    STG(Bg, ldb, n0 + 128, u + 1, 65536 + 49152);   // buf1.B1 <- B1[u+1]
    BAR_; MMQ(0, 1, fb1); BAR_;
    // ph3: Q(1,0); reuse fb0
    RDA(16384);
    STG(Ag, lda, m0, t2, 0);                        // buf0.A0 <- A0[u+2]
    BAR_; MMQ(1, 0, fb0); BAR_;
    // ph4: Q(1,1); reuse fa,fb1; gate: everything older than last 2 stages landed
    STG(Bg, ldb, n0, t2, 32768);                    // buf0.B0 <- B0[u+2]
    BAR_; MMQ(1, 1, fb1); VMW; BAR_;
    // ph5: tile u+1, Q(0,0) from buf1
    RDA(65536); RDB(65536 + 32768, fb0);
    STG(Ag, lda, m0 + 128, t2, 16384);              // buf0.A1 <- A1[u+2]
    BAR_; MMQ(0, 0, fb0); BAR_;
    // ph6
    RDB(65536 + 49152, fb1);
    STG(Bg, ldb, n0 + 128, t2, 49152);              // buf0.B1 <- B1[u+2]
    BAR_; MMQ(0, 1, fb1); BAR_;
    // ph7
    RDA(65536 + 16384);
    STG(Ag, lda, m0, t3, 65536);                    // buf1.A0 <- A0[u+3]
    BAR_; MMQ(1, 0, fb0); BAR_;
    // ph8
    STG(Bg, ldb, n0, t3, 65536 + 32768);            // buf1.B0 <- B0[u+3]
    BAR_; MMQ(1, 1, fb1); VMW; BAR_;
  }

  // epilogue: C/D map col=lane&15, row=(lane>>4)*4+j (verified m89)
#pragma unroll
  for (int qa = 0; qa < 2; ++qa)
#pragma unroll
    for (int qb = 0; qb < 2; ++qb)
#pragma unroll
      for (int fm = 0; fm < 4; ++fm)
#pragma unroll
        for (int fn = 0; fn < 2; ++fn) {
          const int row0 = m0 + qa * 128 + wr * 64 + fm * 16 + lk * 4;
          const int col  = n0 + qb * 128 + wc * 32 + fn * 16 + lm;
          float cb = 0.f;
          if (BIAS_MODE == 1) cb = (col < 2048) ? ba[col] : bb[col - 2048];
          f32x4 v = acc[qa][qb][fm][fn];
#pragma unroll
          for (int j = 0; j < 4; ++j) {
            float x = v[j] + cb;
            if (BIAS_MODE == 2) x += ba[row0 + j];
            const long idx = (long)(row0 + j) * ldd + col;
            if (OUT_BF16) ((u16*)Dg)[idx] = f2bf(x);
            else          ((float*)Dg)[idx] = x;
          }
        }
}

// ---------- row softmax: S[8192][1024] f32 -> P bf16, softmax(alpha*s) ----------
__global__ void softmax_rows(const float* __restrict__ S, u16* __restrict__ P,
                             float alpha) {
  const long row = blockIdx.x;
  const int t = threadIdx.x, l = t & 63, w = t >> 6;
  float4 v = ((const float4*)(S + row * 1024))[t];
  __shared__ float red[8];
  float m = fmaxf(fmaxf(v.x, v.y), fmaxf(v.z, v.w));
#pragma unroll
  for (int off = 32; off; off >>= 1) m = fmaxf(m, __shfl_xor(m, off));
  if (l == 0) red[w] = m;
  __syncthreads();
  m = fmaxf(fmaxf(red[0], red[1]), fmaxf(red[2], red[3]));
  float e0 = __expf((v.x - m) * alpha);
  float e1 = __expf((v.y - m) * alpha);
  float e2 = __expf((v.z - m) * alpha);
  float e3 = __expf((v.w - m) * alpha);
  float s = e0 + e1 + e2 + e3;
#pragma unroll
  for (int off = 32; off; off >>= 1) s += __shfl_xor(s, off);
  if (l == 0) red[4 + w] = s;
  __syncthreads();
  s = red[4] + red[5] + red[6] + red[7];
  const float inv = 1.0f / s;
  ushort4 o;
  o.x = f2bf(e0 * inv); o.y = f2bf(e1 * inv);
  o.z = f2bf(e2 * inv); o.w = f2bf(e3 * inv);
  ((ushort4*)(P + row * 1024))[t] = o;
}

// ---------- F_final = AW[b][0] + AW[b][1] ----------
__global__ void final_add(const float4* __restrict__ aw, float4* __restrict__ dst) {
  const long i = (long)blockIdx.x * 256 + threadIdx.x;  // 2,097,152 quads
  const long b = i >> 19;
  const long r = i & 524287;
  float4 a = aw[b * 1048576 + r];
  float4 c = aw[b * 1048576 + 524288 + r];
  float4 o;
  o.x = a.x + c.x; o.y = a.y + c.y; o.z = a.z + c.z; o.w = a.w + c.w;
  dst[i] = o;
}

// ---------- launch ----------
extern "C" void kernel_launch(void* const* d_in, const int* in_sizes, int n_in,
                              void* d_out, int out_size, void* d_ws, size_t ws_size,
                              hipStream_t stream) {
  (void)in_sizes; (void)n_in; (void)out_size; (void)ws_size;
  const float* F_rgb = (const float*)d_in[0];
  const float* F_ind = (const float*)d_in[1];
  const float* bq_rgb = (const float*)d_in[3];
  const float* bk_rgb = (const float*)d_in[5];
  const float* bv_rgb = (const float*)d_in[7];
  const float* bq_ind = (const float*)d_in[9];
  const float* bk_ind = (const float*)d_in[11];
  const float* bv_ind = (const float*)d_in[13];

  char* ws = (char*)d_ws;
  u16* FT_rgb  = (u16*)(ws);                        // [4][1024][2048] bf16
  u16* FT_ind  = (u16*)(ws + 16777216);
  u16* Wqk_rgb = (u16*)(ws + 33554432);             // [4096][2048] (Wq rows 0-2047, Wk 2048+)
  u16* Wqk_ind = (u16*)(ws + 50331648);
  u16* Wv_rgb  = (u16*)(ws + 67108864);             // [2048][2048]
  u16* Wv_ind  = (u16*)(ws + 75497472);
  u16* QKT_rgb = (u16*)(ws + 83886080);             // [4][1024][4096]  Q|K
  u16* QKT_ind = (u16*)(ws + 117440512);
  u16* V_rgb   = (u16*)(ws + 150994944);            // [4][2048][1024]
  u16* V_ind   = (u16*)(ws + 167772160);
  float* S     = (float*)(ws + 184549376);          // [2][4][1024][1024] f32
  u16*   P     = (u16*)(ws + 218103808);            // [2][4][1024][1024] bf16

  float* out       = (float*)d_out;
  float* out_final = out;                           // [4][2048][1024]
  float* out_Frgb  = out + 8388608;
  float* out_Find  = out + 16777216;
  float* AW        = out + 25165824;                // [4][2][2048][1024]

  // 1) transpose+convert inputs; convert + concat weights
  transpose_cvt<<<dim3(32, 64, 4), dim3(32, 8), 0, stream>>>(F_rgb, FT_rgb);
  transpose_cvt<<<dim3(32, 64, 4), dim3(32, 8), 0, stream>>>(F_ind, FT_ind);
  cvt_bf16<<<4096, 256, 0, stream>>>((const float*)d_in[2],  Wqk_rgb,           1048576);
  cvt_bf16<<<4096, 256, 0, stream>>>((const float*)d_in[4],  Wqk_rgb + 4194304, 1048576);
  cvt_bf16<<<4096, 256, 0, stream>>>((const float*)d_in[8],  Wqk_ind,           1048576);
  cvt_bf16<<<4096, 256, 0, stream>>>((const float*)d_in[10], Wqk_ind + 4194304, 1048576);
  cvt_bf16<<<4096, 256, 0, stream>>>((const float*)d_in[6],  Wv_rgb,            1048576);
  cvt_bf16<<<4096, 256, 0, stream>>>((const float*)d_in[12], Wv_ind,            1048576);

  // 2) fused Q|K convs: QKT[n][o] = sum_c FT[n][c] Wqk[o][c] + b  (col bias, split 2048)
  gemm256<1, 1><<<dim3(16, 4, 4), 512, 0, stream>>>(
      FT_rgb, Wqk_rgb, QKT_rgb, bq_rgb, bk_rgb,
      FT_rgb, Wqk_rgb, QKT_rgb, bq_rgb, bk_rgb,
      8, 2048, 2048, 2048, 4096, 2097152L, 0L, 4194304L);
  gemm256<1, 1><<<dim3(16, 4, 4), 512, 0, stream>>>(
      FT_ind, Wqk_ind, QKT_ind, bq_ind, bk_ind,
      FT_ind, Wqk_ind, QKT_ind, bq_ind, bk_ind,
      8, 2048, 2048, 2048, 4096, 2097152L, 0L, 4194304L);

  // 3) V convs (both inputs in one launch): V[c][n] = sum_k Wv[c][k] FT[n][k] + b[c]
  gemm256<1, 2><<<dim3(4, 8, 8), 512, 0, stream>>>(
      Wv_rgb, FT_rgb, V_rgb, bv_rgb, bv_rgb,
      Wv_ind, FT_ind, V_ind, bv_ind, bv_ind,
      4, 2048, 2048, 2048, 1024, 0L, 2097152L, 2097152L);

  // 4) scores (both directions): S[n][m] = sum_c Q[n][c] K[m][c]
  gemm256<0, 0><<<dim3(4, 4, 8), 512, 0, stream>>>(
      QKT_rgb, QKT_ind + 2048, S, nullptr, nullptr,
      QKT_ind, QKT_rgb + 2048, S + 4194304, nullptr, nullptr,
      4, 2048, 4096, 4096, 1024, 4194304L, 4194304L, 1048576L);

  // 5) softmax rows (scale 1/sqrt(2048) folded in)
  softmax_rows<<<8192, 256, 0, stream>>>(S, P, 0.02209708691207961f);

  // 6) PV (both directions): attended[c][n] = sum_m V[c][m] P[n][m] -> AW slots
  gemm256<0, 0><<<dim3(4, 8, 8), 512, 0, stream>>>(
      V_ind, P, AW, nullptr, nullptr,
      V_rgb, P + 4194304, AW + 2097152, nullptr, nullptr,
      4, 1024, 1024, 1024, 1024, 2097152L, 1048576L, 4194304L);

  // 7) F_final + identity passthroughs
  final_add<<<8192, 256, 0, stream>>>((const float4*)AW, (float4*)out_final);
  hipMemcpyAsync(out_Frgb, F_rgb, 33554432, hipMemcpyDeviceToDevice, stream);
  hipMemcpyAsync(out_Find, F_ind, 33554432, hipMemcpyDeviceToDevice, stream);
}